// Round 2
// baseline (582.981 us; speedup 1.0000x reference)
//
#include <hip/hip_runtime.h>
#include <stdint.h>

#define IN_F   2048
#define OUT_F  2048
#define NROWS  8192   // 4 * 2048
#define BK     64

typedef __bf16 bf16x8 __attribute__((ext_vector_type(8)));
typedef float  f32x16 __attribute__((ext_vector_type(16)));
typedef unsigned short ushort8v __attribute__((ext_vector_type(8)));

// ---------- helpers ----------

__device__ __forceinline__ unsigned short f2bf_rtne(float f) {
    unsigned int u = __float_as_uint(f);
    u += 0x7FFFu + ((u >> 16) & 1u);   // round-to-nearest-even on bf16 boundary
    return (unsigned short)(u >> 16);
}

__device__ __forceinline__ float softplusf(float v) {
    float a = fabsf(v);
    return fmaxf(v, 0.0f) + log1pf(__expf(-a));
}

// async global->LDS, 16B per lane; LDS dest is wave-uniform base + lane*16
__device__ __forceinline__ void gload_lds16(const void* g, void* l) {
    __builtin_amdgcn_global_load_lds(
        (const __attribute__((address_space(1))) unsigned int*)g,
        (__attribute__((address_space(3))) unsigned int*)l,
        16 /*bytes*/, 0 /*offset*/, 0 /*aux*/);
}

// ---------- prep: fused fp32 -> bf16 conversions into workspace ----------
// blocks [0, 8192): x -> xb   (8 elems/thread, 16B stores)
// blocks [8192, 10240): mu/sigma -> kh (keys), mh (mu)

__global__ __launch_bounds__(256)
void prep_kernel(const float* __restrict__ x, const float* __restrict__ mu,
                 const float* __restrict__ sg,
                 unsigned short* __restrict__ xb, unsigned short* __restrict__ kh,
                 unsigned short* __restrict__ mh) {
    const int b = blockIdx.x;
    const int t = threadIdx.x;
    if (b < 8192) {
        const size_t i = ((size_t)b * 256 + t) * 8;
        float4 v0 = *(const float4*)(x + i);
        float4 v1 = *(const float4*)(x + i + 4);
        ushort8v o;
        o[0] = f2bf_rtne(v0.x); o[1] = f2bf_rtne(v0.y);
        o[2] = f2bf_rtne(v0.z); o[3] = f2bf_rtne(v0.w);
        o[4] = f2bf_rtne(v1.x); o[5] = f2bf_rtne(v1.y);
        o[6] = f2bf_rtne(v1.z); o[7] = f2bf_rtne(v1.w);
        *(ushort8v*)(xb + i) = o;
    } else {
        const size_t i = ((size_t)(b - 8192) * 256 + t) * 8;
        float4 m0 = *(const float4*)(mu + i);
        float4 m1 = *(const float4*)(mu + i + 4);
        float4 s0 = *(const float4*)(sg + i);
        float4 s1 = *(const float4*)(sg + i + 4);
        ushort8v ko, mo;
        ko[0] = f2bf_rtne(m0.x * softplusf(s0.x));
        ko[1] = f2bf_rtne(m0.y * softplusf(s0.y));
        ko[2] = f2bf_rtne(m0.z * softplusf(s0.z));
        ko[3] = f2bf_rtne(m0.w * softplusf(s0.w));
        ko[4] = f2bf_rtne(m1.x * softplusf(s1.x));
        ko[5] = f2bf_rtne(m1.y * softplusf(s1.y));
        ko[6] = f2bf_rtne(m1.z * softplusf(s1.z));
        ko[7] = f2bf_rtne(m1.w * softplusf(s1.w));
        mo[0] = f2bf_rtne(m0.x); mo[1] = f2bf_rtne(m0.y);
        mo[2] = f2bf_rtne(m0.z); mo[3] = f2bf_rtne(m0.w);
        mo[4] = f2bf_rtne(m1.x); mo[5] = f2bf_rtne(m1.y);
        mo[6] = f2bf_rtne(m1.z); mo[7] = f2bf_rtne(m1.w);
        *(ushort8v*)(kh + i) = ko;
        *(ushort8v*)(mh + i) = mo;
    }
}

// ---------- fused double-GEMM ----------
// C-tile 128x128 per block, 256 threads = 4 waves, each wave owns a 64x64
// quadrant = 2x2 grid of 32x32x16 bf16 MFMAs x 2 accumulator sets sharing A.
// BK=64 (48 KB LDS, 3 blocks/CU). LDS k-chunk position XOR-swizzled by
// (row&7) — implemented by permuting each lane's DMA *source* chunk, since
// the DMA dest must stay base+lane*16.

__global__ __launch_bounds__(256, 3)
void gemm_fused_kernel(const unsigned short* __restrict__ xb,  // [8192][2048] bf16
                       const unsigned short* __restrict__ kh,  // [2048][2048] bf16 keys
                       const unsigned short* __restrict__ mh,  // [2048][2048] bf16 mu
                       const float* __restrict__ gate,         // [2048]
                       float* __restrict__ out0,               // masked  [8192][2048]
                       float* __restrict__ out1,               // scores  [8192][2048]
                       float* __restrict__ out2)               // masked  [8192][2048]
{
    __shared__ __align__(16) unsigned short As[128 * BK];
    __shared__ __align__(16) unsigned short Ks[128 * BK];
    __shared__ __align__(16) unsigned short Ms[128 * BK];

    const int tid  = threadIdx.x;
    const int lane = tid & 63;
    const int wv   = tid >> 6;

    const int bm = blockIdx.x;   // 0..63 over N rows
    const int bo = blockIdx.y;   // 0..15 over output features

    const int wm = (wv >> 1) * 64;   // wave quadrant in C tile
    const int wn = (wv & 1) * 64;

    // staging: region = 1KB = 8 rows x 128B. lane covers 16B slot (lane&7)
    // of row (lane>>3). Source chunk swizzled: g = slot ^ (row&7).
    const int srow = lane >> 3;
    const int scol = ((lane & 7) ^ srow) * 8;   // element offset in BK window

    f32x16 accS[2][2];
    f32x16 accC[2][2];
#pragma unroll
    for (int i = 0; i < 2; i++)
#pragma unroll
        for (int j = 0; j < 2; j++)
#pragma unroll
            for (int r = 0; r < 16; r++) {
                accS[i][j][r] = 0.f;
                accC[i][j][r] = 0.f;
            }

    const unsigned short* xg = xb + (size_t)(bm * 128) * IN_F;
    const unsigned short* kg = kh + (size_t)(bo * 128) * IN_F;
    const unsigned short* mg = mh + (size_t)(bo * 128) * IN_F;

    // fragment coords: A[m=lane&31][k=(lane>>5)*8+j]; B symmetric (B^T rows)
    const int fm = lane & 31;
    const int hi = lane >> 5;
    const int rA0 = wm + fm,      rA1 = wm + 32 + fm;
    const int rB0 = wn + fm,      rB1 = wn + 32 + fm;
    const int swA0 = rA0 & 7,     swA1 = rA1 & 7;
    const int swB0 = rB0 & 7,     swB1 = rB1 & 7;

    for (int kt = 0; kt < IN_F; kt += BK) {
        __syncthreads();   // prior iter's fragment reads done before overwrite
        // 16 regions per array; wave w stages regions [w*4, w*4+4)
#pragma unroll
        for (int j = 0; j < 4; j++) {
            const int c = wv * 4 + j;
            const int r = c * 8 + srow;
            const size_t goff = (size_t)r * IN_F + kt + scol;
            gload_lds16(xg + goff, &As[c * 512]);
            gload_lds16(kg + goff, &Ks[c * 512]);
            gload_lds16(mg + goff, &Ms[c * 512]);
        }
        __syncthreads();   // staging visible

#pragma unroll
        for (int s = 0; s < 4; s++) {
            const int t0 = s * 2 + hi;    // 16B k-chunk wanted this k-step
            bf16x8 af0 = *(const bf16x8*)&As[rA0 * 64 + ((t0 ^ swA0) * 8)];
            bf16x8 af1 = *(const bf16x8*)&As[rA1 * 64 + ((t0 ^ swA1) * 8)];

            bf16x8 kf0 = *(const bf16x8*)&Ks[rB0 * 64 + ((t0 ^ swB0) * 8)];
            bf16x8 mf0 = *(const bf16x8*)&Ms[rB0 * 64 + ((t0 ^ swB0) * 8)];
            accS[0][0] = __builtin_amdgcn_mfma_f32_32x32x16_bf16(af0, kf0, accS[0][0], 0, 0, 0);
            accS[1][0] = __builtin_amdgcn_mfma_f32_32x32x16_bf16(af1, kf0, accS[1][0], 0, 0, 0);
            accC[0][0] = __builtin_amdgcn_mfma_f32_32x32x16_bf16(af0, mf0, accC[0][0], 0, 0, 0);
            accC[1][0] = __builtin_amdgcn_mfma_f32_32x32x16_bf16(af1, mf0, accC[1][0], 0, 0, 0);

            bf16x8 kf1 = *(const bf16x8*)&Ks[rB1 * 64 + ((t0 ^ swB1) * 8)];
            bf16x8 mf1 = *(const bf16x8*)&Ms[rB1 * 64 + ((t0 ^ swB1) * 8)];
            accS[0][1] = __builtin_amdgcn_mfma_f32_32x32x16_bf16(af0, kf1, accS[0][1], 0, 0, 0);
            accS[1][1] = __builtin_amdgcn_mfma_f32_32x32x16_bf16(af1, kf1, accS[1][1], 0, 0, 0);
            accC[0][1] = __builtin_amdgcn_mfma_f32_32x32x16_bf16(af0, mf1, accC[0][1], 0, 0, 0);
            accC[1][1] = __builtin_amdgcn_mfma_f32_32x32x16_bf16(af1, mf1, accC[1][1], 0, 0, 0);
        }
    }

    // epilogue: 32x32 C/D layout: col = lane&31, row = (reg&3) + 8*(reg>>2) + 4*hi
    const float inv_sqrt_d = 0.022097086912079608f;  // 1/sqrt(2048)
    const size_t row_base = (size_t)bm * 128 + wm;
    const int    col_base = bo * 128 + wn;

#pragma unroll
    for (int tj = 0; tj < 2; tj++) {
        const int col = col_base + tj * 32 + fm;
        const float g = gate[col];
#pragma unroll
        for (int ti = 0; ti < 2; ti++) {
#pragma unroll
            for (int reg = 0; reg < 16; reg++) {
                const int ro = (reg & 3) + 8 * (reg >> 2) + 4 * hi;
                const size_t row = row_base + ti * 32 + ro;
                const size_t idx = row * OUT_F + col;
                const float s = accS[ti][tj][reg] * inv_sqrt_d;
                const float c = accC[ti][tj][reg];
                float w = s - g;
                w = w > 0.f ? w : 0.f;
                const float m = c * w;
                out0[idx] = m;
                out1[idx] = s;
                out2[idx] = m;
            }
        }
    }
}

// ---------- launch ----------

extern "C" void kernel_launch(void* const* d_in, const int* in_sizes, int n_in,
                              void* d_out, int out_size, void* d_ws, size_t ws_size,
                              hipStream_t stream) {
    const float* x    = (const float*)d_in[0];   // [4,2048,2048]
    const float* mu   = (const float*)d_in[1];   // [2048,2048]
    const float* sg   = (const float*)d_in[2];   // [2048,2048]
    const float* gate = (const float*)d_in[3];   // [2048]

    float* out0 = (float*)d_out;                         // final_output
    float* out1 = out0 + (size_t)NROWS * OUT_F;          // scores
    float* out2 = out1 + (size_t)NROWS * OUT_F;          // masked_output

    // workspace layout (bf16): xb 33.55MB | kh 8.39MB | mh 8.39MB  (50.3MB)
    unsigned short* xb = (unsigned short*)d_ws;
    unsigned short* kh = xb + (size_t)NROWS * IN_F;
    unsigned short* mh = kh + (size_t)OUT_F * IN_F;

    prep_kernel<<<8192 + 2048, 256, 0, stream>>>(x, mu, sg, xb, kh, mh);

    dim3 grid(NROWS / 128, OUT_F / 128);  // 64 x 16
    gemm_fused_kernel<<<grid, 256, 0, stream>>>(xb, kh, mh, gate, out0, out1, out2);
}

// Round 3
// 407.686 us; speedup vs baseline: 1.4300x; 1.4300x over previous
//
#include <hip/hip_runtime.h>
#include <stdint.h>

#define IN_F   2048
#define OUT_F  2048
#define NROWS  8192   // 4 * 2048
#define BK     64
#define MT     128    // block M tile
#define NT     64     // block N tile

typedef __bf16 bf16x8 __attribute__((ext_vector_type(8)));
typedef float  f32x16 __attribute__((ext_vector_type(16)));
typedef unsigned short ushort8v __attribute__((ext_vector_type(8)));

// ---------- helpers ----------

__device__ __forceinline__ unsigned short f2bf_rtne(float f) {
    unsigned int u = __float_as_uint(f);
    u += 0x7FFFu + ((u >> 16) & 1u);   // round-to-nearest-even on bf16 boundary
    return (unsigned short)(u >> 16);
}

__device__ __forceinline__ float softplusf(float v) {
    float a = fabsf(v);
    return fmaxf(v, 0.0f) + log1pf(__expf(-a));
}

// async global->LDS, 16B per lane; LDS dest is wave-uniform base + lane*16
__device__ __forceinline__ void gload_lds16(const void* g, void* l) {
    __builtin_amdgcn_global_load_lds(
        (const __attribute__((address_space(1))) unsigned int*)g,
        (__attribute__((address_space(3))) unsigned int*)l,
        16 /*bytes*/, 0 /*offset*/, 0 /*aux*/);
}

// ---------- prep: fused fp32 -> bf16 conversions into workspace ----------

__global__ __launch_bounds__(256)
void prep_kernel(const float* __restrict__ x, const float* __restrict__ mu,
                 const float* __restrict__ sg,
                 unsigned short* __restrict__ xb, unsigned short* __restrict__ kh,
                 unsigned short* __restrict__ mh) {
    const int b = blockIdx.x;
    const int t = threadIdx.x;
    if (b < 8192) {
        const size_t i = ((size_t)b * 256 + t) * 8;
        float4 v0 = *(const float4*)(x + i);
        float4 v1 = *(const float4*)(x + i + 4);
        ushort8v o;
        o[0] = f2bf_rtne(v0.x); o[1] = f2bf_rtne(v0.y);
        o[2] = f2bf_rtne(v0.z); o[3] = f2bf_rtne(v0.w);
        o[4] = f2bf_rtne(v1.x); o[5] = f2bf_rtne(v1.y);
        o[6] = f2bf_rtne(v1.z); o[7] = f2bf_rtne(v1.w);
        *(ushort8v*)(xb + i) = o;
    } else {
        const size_t i = ((size_t)(b - 8192) * 256 + t) * 8;
        float4 m0 = *(const float4*)(mu + i);
        float4 m1 = *(const float4*)(mu + i + 4);
        float4 s0 = *(const float4*)(sg + i);
        float4 s1 = *(const float4*)(sg + i + 4);
        ushort8v ko, mo;
        ko[0] = f2bf_rtne(m0.x * softplusf(s0.x));
        ko[1] = f2bf_rtne(m0.y * softplusf(s0.y));
        ko[2] = f2bf_rtne(m0.z * softplusf(s0.z));
        ko[3] = f2bf_rtne(m0.w * softplusf(s0.w));
        ko[4] = f2bf_rtne(m1.x * softplusf(s1.x));
        ko[5] = f2bf_rtne(m1.y * softplusf(s1.y));
        ko[6] = f2bf_rtne(m1.z * softplusf(s1.z));
        ko[7] = f2bf_rtne(m1.w * softplusf(s1.w));
        mo[0] = f2bf_rtne(m0.x); mo[1] = f2bf_rtne(m0.y);
        mo[2] = f2bf_rtne(m0.z); mo[3] = f2bf_rtne(m0.w);
        mo[4] = f2bf_rtne(m1.x); mo[5] = f2bf_rtne(m1.y);
        mo[6] = f2bf_rtne(m1.z); mo[7] = f2bf_rtne(m1.w);
        *(ushort8v*)(kh + i) = ko;
        *(ushort8v*)(mh + i) = mo;
    }
}

// ---------- fused double-GEMM ----------
// Block tile 128(M)x64(N), 4 waves, wave tile 64x32 = 2x1 grid of 32x32x16
// MFMAs x 2 acc sets (scores/comp) sharing A. acc = 64 regs/lane -> target
// 4 waves/SIMD, 4 blocks/CU (32 KB LDS each). Grid 64x32 = 2048 blocks =
// exactly 2 residency phases. LDS rows are 128B = 8 x 16B chunks; chunk
// position XOR-swizzled by (row&7) on the DMA *source* side so fragment
// ds_read_b128s land 2-way max (free).

__global__ __launch_bounds__(256, 4)
void gemm_fused_kernel(const unsigned short* __restrict__ xb,  // [8192][2048] bf16
                       const unsigned short* __restrict__ kh,  // [2048][2048] bf16 keys
                       const unsigned short* __restrict__ mh,  // [2048][2048] bf16 mu
                       const float* __restrict__ gate,         // [2048]
                       float* __restrict__ out0,               // masked  [8192][2048]
                       float* __restrict__ out1,               // scores  [8192][2048]
                       float* __restrict__ out2)               // masked  [8192][2048]
{
    __shared__ __align__(16) unsigned short As[MT * BK];  // 16 KB
    __shared__ __align__(16) unsigned short Ks[NT * BK];  //  8 KB
    __shared__ __align__(16) unsigned short Ms[NT * BK];  //  8 KB

    const int tid  = threadIdx.x;
    const int lane = tid & 63;
    const int wv   = tid >> 6;

    const int bm = blockIdx.x;   // 0..63 over rows
    const int bo = blockIdx.y;   // 0..31 over output features

    const int wm = (wv >> 1) * 64;   // wave M offset in block tile
    const int wn = (wv & 1) * 32;    // wave N offset

    // staging: region = 1KB = 8 rows x 128B; lane covers 16B chunk (lane&7)
    // of row (lane>>3); source chunk swizzled by row&7 (= srow).
    const int srow = lane >> 3;
    const int scol = ((lane & 7) ^ srow) * 8;

    f32x16 accS[2], accC[2];
#pragma unroll
    for (int i = 0; i < 2; i++)
#pragma unroll
        for (int r = 0; r < 16; r++) { accS[i][r] = 0.f; accC[i][r] = 0.f; }

    const unsigned short* xg = xb + (size_t)(bm * MT) * IN_F;
    const unsigned short* kg = kh + (size_t)(bo * NT) * IN_F;
    const unsigned short* mg = mh + (size_t)(bo * NT) * IN_F;

    // fragment coords: A[m=lane&31][k=hi*8+j]; B^T rows likewise
    const int fm = lane & 31;
    const int hi = lane >> 5;
    const int rA0 = wm + fm, rA1 = wm + 32 + fm;
    const int rB  = wn + fm;
    const int sw  = fm & 7;   // same for rA0, rA1, rB (offsets multiple of 8)

    const float g = gate[bo * NT + wn + fm];   // one gate value per lane

    for (int kt = 0; kt < IN_F; kt += BK) {
        __syncthreads();   // prior iter's fragment reads done before overwrite
        // As: 16 regions, 4/wave; Ks/Ms: 8 regions, 2/wave
#pragma unroll
        for (int j = 0; j < 4; j++) {
            const int c = wv * 4 + j;
            const size_t goff = (size_t)(c * 8 + srow) * IN_F + kt + scol;
            gload_lds16(xg + goff, &As[c * 512]);
        }
#pragma unroll
        for (int j = 0; j < 2; j++) {
            const int c = wv * 2 + j;
            const size_t goff = (size_t)(c * 8 + srow) * IN_F + kt + scol;
            gload_lds16(kg + goff, &Ks[c * 512]);
            gload_lds16(mg + goff, &Ms[c * 512]);
        }
        __syncthreads();   // staging visible

#pragma unroll
        for (int s = 0; s < 4; s++) {
            const int t0 = s * 2 + hi;    // logical 16B k-chunk this k-step
            bf16x8 af0 = *(const bf16x8*)&As[rA0 * BK + ((t0 ^ sw) * 8)];
            bf16x8 af1 = *(const bf16x8*)&As[rA1 * BK + ((t0 ^ sw) * 8)];
            bf16x8 kf  = *(const bf16x8*)&Ks[rB  * BK + ((t0 ^ sw) * 8)];
            bf16x8 mf  = *(const bf16x8*)&Ms[rB  * BK + ((t0 ^ sw) * 8)];
            accS[0] = __builtin_amdgcn_mfma_f32_32x32x16_bf16(af0, kf, accS[0], 0, 0, 0);
            accS[1] = __builtin_amdgcn_mfma_f32_32x32x16_bf16(af1, kf, accS[1], 0, 0, 0);
            accC[0] = __builtin_amdgcn_mfma_f32_32x32x16_bf16(af0, mf, accC[0], 0, 0, 0);
            accC[1] = __builtin_amdgcn_mfma_f32_32x32x16_bf16(af1, mf, accC[1], 0, 0, 0);
        }
    }

    // epilogue: 32x32 C/D layout: col = lane&31, row = (reg&3)+8*(reg>>2)+4*hi
    const float inv_sqrt_d = 0.022097086912079608f;  // 1/sqrt(2048)
    const size_t row_base = (size_t)bm * MT + wm;
    const int    col      = bo * NT + wn + fm;

#pragma unroll
    for (int ti = 0; ti < 2; ti++) {
#pragma unroll
        for (int reg = 0; reg < 16; reg++) {
            const int ro = (reg & 3) + 8 * (reg >> 2) + 4 * hi;
            const size_t row = row_base + ti * 32 + ro;
            const size_t idx = row * OUT_F + col;
            const float s = accS[ti][reg] * inv_sqrt_d;
            const float c = accC[ti][reg];
            float w = s - g;
            w = w > 0.f ? w : 0.f;
            const float m = c * w;
            out0[idx] = m;
            out1[idx] = s;
            out2[idx] = m;
        }
    }
}

// ---------- launch ----------

extern "C" void kernel_launch(void* const* d_in, const int* in_sizes, int n_in,
                              void* d_out, int out_size, void* d_ws, size_t ws_size,
                              hipStream_t stream) {
    const float* x    = (const float*)d_in[0];   // [4,2048,2048]
    const float* mu   = (const float*)d_in[1];   // [2048,2048]
    const float* sg   = (const float*)d_in[2];   // [2048,2048]
    const float* gate = (const float*)d_in[3];   // [2048]

    float* out0 = (float*)d_out;                         // final_output
    float* out1 = out0 + (size_t)NROWS * OUT_F;          // scores
    float* out2 = out1 + (size_t)NROWS * OUT_F;          // masked_output

    // workspace layout (bf16): xb 33.55MB | kh 8.39MB | mh 8.39MB  (50.3MB)
    unsigned short* xb = (unsigned short*)d_ws;
    unsigned short* kh = xb + (size_t)NROWS * IN_F;
    unsigned short* mh = kh + (size_t)OUT_F * IN_F;

    prep_kernel<<<8192 + 2048, 256, 0, stream>>>(x, mu, sg, xb, kh, mh);

    dim3 grid(NROWS / MT, OUT_F / NT);  // 64 x 32 = 2048 blocks
    gemm_fused_kernel<<<grid, 256, 0, stream>>>(xb, kh, mh, gate, out0, out1, out2);
}